// Round 11
// baseline (145.609 us; speedup 1.0000x reference)
//
#include <hip/hip_runtime.h>

// LSTM: B=16384, T=1024, I=1, H=2, C=4.
// 2 lanes per batch element: lane (2e+j) owns hidden unit j of element e.
//
// R11: ALL-RATIONAL step — the per-step serial chain contains ZERO exp2 and
// ONE rcp (was: exp2 + 2 rcp, ~244 cy/step, trans-latency-bound).
//  * Every gate uses Pade[5/4] tanh polys p(u)=u^2+105u+945, q(u)=15u^2+420u+945:
//      sigma(x) = (q + t*p)/(2q), t = clamp(x/2, +-3.5)   [0.5 folded into weights]
//      tanh(g)  = zg*p/q,         zg = clamp(g, +-3.5)
//    Same p,q for all 4 gates -> packed f32x2 evaluation (2 gates/inst).
//  * Cell state carried as a RATIO c = N/D (scale-free):
//      N' = Sfn*N*(qi*qg) + (Sin*Gn)*(qf*D),  D' = (qf*D)*(qi*qg)
//    (Sfn = qf + tf*pf etc., Gn = zg*pg). True denom = 2*D'; the 2 and the
//    exponent of D' are removed by an exponent-only bit-hack normalization
//    (R8-proven): Dm = mantissa(D') in [1,2), Nm = N' * 2^(-E-1). Pure int VALU.
//  * h' = tanh(Nm/Dm)*sigma(o) via homogeneous Pade (R10-validated):
//      zN = med3(Nm, -4Dm, 4Dm); a=zN^2, b=Dm^2
//      numer = zN*(0.5*Son)*(a^2+105ab+945b^2)   [0.5*Son folded into coeffs]
//      den   = (Dm*qo)*(15a^2+420ab+945b^2)
//      h' = numer * rcp(den)            <- the ONLY trans op on the chain
//  * c-chain (Nm,Dm) completes ~6 links BEFORE hm -> well off-critical
//    (fixes R8's fatal flaw where c depended on the late rcp).
//
// Stability: clamped Pade ratio <= 0.99923 < 1 => sigma_f < 1 always (no
// exponential c growth). Clamp-boundary sigma err <=5e-4 needs |pre|>7
// (~5.5-sigma of x): ~one-off in 16.7M gate evals. Threshold is 1.4e-2.
//
// Gate rows (PyTorch order): i: 0,1  f: 2,3  g: 4,5  o: 6,7

typedef float f32x2 __attribute__((ext_vector_type(2)));

static __device__ __forceinline__ float fast_rcp(float x) { return __builtin_amdgcn_rcpf(x); }
static __device__ __forceinline__ float fmed3(float x, float lo, float hi) {
    return __builtin_amdgcn_fmed3f(x, lo, hi);
}

// Swap values between lane pairs (0<->1, 2<->3, ...) via DPP quad_perm.
static __device__ __forceinline__ float dpp_swap1(float v) {
    int i = __builtin_bit_cast(int, v);
    i = __builtin_amdgcn_mov_dpp(i, 0xB1, 0xF, 0xF, false);
    return __builtin_bit_cast(float, i);
}

__global__ __launch_bounds__(64, 1) void lstm_fused7(
    const float* __restrict__ x,      // [B, T, 1]
    const float* __restrict__ W_ih,   // [8, 1]
    const float* __restrict__ W_hh,   // [8, 2]
    const float* __restrict__ b_ih,   // [8]
    const float* __restrict__ b_hh,   // [8]
    const float* __restrict__ W_fc,   // [4, 2]
    const float* __restrict__ b_fc,   // [4]
    float* __restrict__ out,          // [B, 4]
    int T)
{
    const int tid = blockIdx.x * 64 + threadIdx.x;
    const int e   = tid >> 1;          // batch element
    const int j   = tid & 1;           // hidden unit owned by this lane

    // Per-lane scaled weights for my unit's 4 gates (k: 0=i,1=f,2=g,3=o).
    // Scale: 0.5 for sigma gates (t = x/2), 1.0 for g (direct tanh).
    float wihs[4], whm[4], whp[4], bbs[4];
#pragma unroll
    for (int k = 0; k < 4; ++k) {
        const int g = 2 * k + j;                         // gate row
        const float s = (k == 2) ? 1.0f : 0.5f;
        wihs[k] = s * W_ih[g];
        whm[k]  = s * W_hh[2 * g + j];
        whp[k]  = s * W_hh[2 * g + (j ^ 1)];
        bbs[k]  = s * (b_ih[g] + b_hh[g]);
    }

    f32x2 wihs2[2], whm2[2], whp2[2], bbs2[2];
#pragma unroll
    for (int q = 0; q < 2; ++q) {
        wihs2[q] = f32x2{wihs[2*q], wihs[2*q+1]};
        whm2[q]  = f32x2{whm[2*q],  whm[2*q+1]};
        whp2[q]  = f32x2{whp[2*q],  whp[2*q+1]};
        bbs2[q]  = f32x2{bbs[2*q],  bbs[2*q+1]};
    }

    // Packed Pade[5/4] coefficients (loop-invariant, hoisted to regs).
    const f32x2 c105 = {105.f, 105.f};
    const f32x2 c945 = {945.f, 945.f};
    const f32x2 c15  = {15.f,  15.f};
    const f32x2 c420 = {420.f, 420.f};

    float hm = 0.f;   // my unit's h
    float hp = 0.f;   // partner unit's h
    float Nn = 0.f;   // c = Nn/Dd (ratio-carried cell state)
    float Dd = 1.f;

    const float4* xv = reinterpret_cast<const float4*>(x + (size_t)e * (size_t)T);
    const int nt4 = T >> 2;

    for (int t4 = 0; t4 < nt4; ++t4) {
        const float4 xq = xv[t4];
        const float xs[4] = {xq.x, xq.y, xq.z, xq.w};

        // h-independent x-terms for 4 timesteps (packed fma, off-chain).
        f32x2 xterm[4][2];
#pragma unroll
        for (int u = 0; u < 4; ++u) {
            const f32x2 xu = f32x2{xs[u], xs[u]};
#pragma unroll
            for (int q = 0; q < 2; ++q)
                xterm[u][q] = __builtin_elementwise_fma(xu, wihs2[q], bbs2[q]);
        }

#pragma unroll
        for (int u = 0; u < 4; ++u) {
            const f32x2 hmv = f32x2{hm, hm};
            const f32x2 hpv = f32x2{hp, hp};
            // (ti, tf) and (zg, to): sigma gates pre-scaled by 0.5.
            const f32x2 pre01 = __builtin_elementwise_fma(
                whm2[0], hmv, __builtin_elementwise_fma(whp2[0], hpv, xterm[u][0]));
            const f32x2 pre23 = __builtin_elementwise_fma(
                whm2[1], hmv, __builtin_elementwise_fma(whp2[1], hpv, xterm[u][1]));

            // Clamp all 4 (f,g for stability; i,o cheap + bounded err).
            const f32x2 tc01 = { fmed3(pre01.x, -3.5f, 3.5f),
                                 fmed3(pre01.y, -3.5f, 3.5f) };
            const f32x2 tc23 = { fmed3(pre23.x, -3.5f, 3.5f),
                                 fmed3(pre23.y, -3.5f, 3.5f) };

            // Shared Pade[5/4] polys, packed (2 gates per instruction).
            const f32x2 u01 = tc01 * tc01;
            const f32x2 u23 = tc23 * tc23;
            const f32x2 p01 = __builtin_elementwise_fma(u01 + c105, u01, c945);
            const f32x2 p23 = __builtin_elementwise_fma(u23 + c105, u23, c945);
            const f32x2 q01 = __builtin_elementwise_fma(
                __builtin_elementwise_fma(c15, u01, c420), u01, c945);
            const f32x2 q23 = __builtin_elementwise_fma(
                __builtin_elementwise_fma(c15, u23, c420), u23, c945);

            // Scalar finish per gate.
            const float Sin = fmaf(tc01.x, p01.x, q01.x);   // 2*qi*sigma(i)
            const float Sfn = fmaf(tc01.y, p01.y, q01.y);   // 2*qf*sigma(f)
            const float Gn  = tc23.x * p23.x;               // qg*tanh(g)
            const float Son = fmaf(tc23.y, p23.y, q23.y);   // 2*qo*sigma(o)

            // sigma(o) folds into numerator coefficients (off-chain, early).
            const float cS52  = 52.5f  * Son;
            const float cS945 = 472.5f * Son;
            const float cShalf= 0.5f   * Son;

            // Ratio update of c (no division).
            const float QQ    = q01.x * q23.x;              // qi*qg
            const float SfnN  = Sfn * Nn;
            const float T1    = SfnN * QQ;
            const float SinGn = Sin * Gn;
            const float qfD   = q01.y * Dd;
            const float Nr    = fmaf(SinGn, qfD, T1);       // N'
            const float Dr    = qfD * QQ;                   // D' (true denom 2*Dr)

            // Exponent-only normalization: Dm in [1,2), Nm = Nr*2^(-E-1).
            const unsigned Di = __builtin_bit_cast(unsigned, Dr);
            const float Dm = __builtin_bit_cast(float,
                                (Di & 0x007FFFFFu) | 0x3F800000u);
            const float sc = __builtin_bit_cast(float,
                                0x7E800000u - (Di & 0x7F800000u));
            const float Nm = Nr * sc;                       // c' = Nm/Dm

            // h' = tanh(Nm/Dm)*sigma(o): homogeneous Pade, ONE rcp.
            const float B4 = 4.0f * Dm;
            const float zN = fmed3(Nm, -B4, B4);
            const float a  = zN * zN;
            const float b  = Dm * Dm;
            const float ab = a * b;
            const float b2 = b * b;

            const float t945s = cS945 * b2;
            const float p1s   = fmaf(cS52, ab, t945s);
            const float haS   = cShalf * a;
            const float phs   = fmaf(haS, a, p1s);          // 0.5*Son*P(a,b)
            const float numer = zN * phs;

            const float t945b = 945.f * b2;
            const float q1    = fmaf(420.f, ab, t945b);
            const float a15   = 15.f * a;
            const float qh    = fmaf(a15, a, q1);           // Q(a,b)
            const float DmQo  = Dm * q23.y;
            const float den   = DmQo * qh;

            const float r = fast_rcp(den);                  // the ONLY trans op
            hm = numer * r;                                 // tanh(c')*sigma(o)

            hp = dpp_swap1(hm);                             // lane-pair swap
            Nn = Nm; Dd = Dm;                               // off-critical carry
        }
    }

    // Final FC: out[e,:] = h @ W_fc^T + b_fc.  Even lane -> classes 0,1;
    // odd lane -> classes 2,3. Lane pair writes one contiguous 16B row.
    const float h0 = j ? hp : hm;
    const float h1 = j ? hm : hp;
    const int   c0 = 2 * j;
    const float o0 = fmaf(W_fc[2*c0+0], h0, fmaf(W_fc[2*c0+1], h1, b_fc[c0]));
    const float o1 = fmaf(W_fc[2*c0+2], h0, fmaf(W_fc[2*c0+3], h1, b_fc[c0+1]));
    float2 r2; r2.x = o0; r2.y = o1;
    reinterpret_cast<float2*>(out)[e * 2 + j] = r2;
}

extern "C" void kernel_launch(void* const* d_in, const int* in_sizes, int n_in,
                              void* d_out, int out_size, void* d_ws, size_t ws_size,
                              hipStream_t stream) {
    const float* x    = (const float*)d_in[0];
    const float* W_ih = (const float*)d_in[1];
    const float* W_hh = (const float*)d_in[2];
    const float* b_ih = (const float*)d_in[3];
    const float* b_hh = (const float*)d_in[4];
    const float* W_fc = (const float*)d_in[5];
    const float* b_fc = (const float*)d_in[6];
    float* out = (float*)d_out;

    const int T = 1024;
    const int B = in_sizes[0] / T;   // I == 1

    dim3 block(64);
    dim3 grid((B * 2) / 64);         // 2 lanes/element -> 512 waves, 2 waves/CU
    lstm_fused7<<<grid, block, 0, stream>>>(x, W_ih, W_hh, b_ih, b_hh, W_fc, b_fc, out, T);
}